// Round 5
// baseline (326.400 us; speedup 1.0000x reference)
//
#include <hip/hip_runtime.h>
#include <hip/hip_bf16.h>
#include <cstdint>
#include <cstddef>

#define DEVFN static __device__ __forceinline__

typedef __attribute__((ext_vector_type(8))) short bf16x8;
typedef __attribute__((ext_vector_type(16))) float f32x16;

static constexpr int kB = 8192;
static constexpr int kIN = 1024;
static constexpr int kH = 2048;

DEVFN unsigned short f32_to_bf16(float f) {
  union { float f; unsigned int u; } v; v.f = f;
  unsigned int x = v.u;
  x += 0x7fffu + ((x >> 16) & 1u);   // round-to-nearest-even
  return (unsigned short)(x >> 16);
}
DEVFN float bf16_to_f32(unsigned short u) {
  union { unsigned int u; float f; } v; v.u = (unsigned int)u << 16;
  return v.f;
}

// one fused cast pass: fp32 -> bf16 for all five panels (vec4 per thread)
__global__ void cast_all(const float* __restrict__ x, const float* __restrict__ Wx,
                         const float* __restrict__ Wh, const float* __restrict__ Uz,
                         const float* __restrict__ h,
                         unsigned short* __restrict__ xb, unsigned short* __restrict__ Wxb,
                         unsigned short* __restrict__ Wcat, unsigned short* __restrict__ Acat) {
  const long i = (long)blockIdx.x * blockDim.x + threadIdx.x;  // vec4 index
  const float* src; unsigned short* dst; int sh, stride, off; long li;
  if (i < 2097152L)      { li = i;            src = x;  dst = xb;   sh = 8; stride = 1024; off = 0; }
  else if (i < 2621440L) { li = i - 2097152L; src = Wx; dst = Wxb;  sh = 8; stride = 1024; off = 0; }
  else if (i < 3670016L) { li = i - 2621440L; src = Wh; dst = Wcat; sh = 9; stride = 4096; off = 0; }
  else if (i < 4718592L) { li = i - 3670016L; src = Uz; dst = Wcat; sh = 9; stride = 4096; off = 2048; }
  else                   { li = i - 4718592L; src = h;  dst = Acat; sh = 9; stride = 4096; off = 0; }
  float4 v = *(const float4*)(src + li * 4);
  const long row = li >> sh;
  const long col = (li & ((1L << sh) - 1)) * 4;
  unsigned short* d = dst + row * stride + off + col;
  ushort4 o;
  o.x = f32_to_bf16(v.x); o.y = f32_to_bf16(v.y);
  o.z = f32_to_bf16(v.z); o.w = f32_to_bf16(v.w);
  *(ushort4*)d = o;
}

typedef const __attribute__((address_space(1))) unsigned int* gptr_t;
typedef __attribute__((address_space(3))) unsigned int* lptr_t;
DEVFN void gload16(const unsigned short* g, unsigned short* l) {
  __builtin_amdgcn_global_load_lds((gptr_t)g, (lptr_t)l, 16, 0, 0);
}

DEVFN void bar() { __builtin_amdgcn_s_barrier(); }
#define LGKM0() asm volatile("s_waitcnt lgkmcnt(0)" ::: "memory")
#define VMC4()  asm volatile("s_waitcnt vmcnt(4)" ::: "memory")

// LDS geometry: 8 regions of [128 rows][64 bf16] (16 KiB each) = 128 KiB.
// region = buf*4 + op*2 + half   (op: 0=A, 1=B; half: wave-row/col group)
// Swizzle (T2): element col stored at  c ^ ((row&7)*8)  (byte ^= (row&7)<<4).
// global_load_lds writes LINEAR; global SOURCE col is pre-swizzled (rule 21).
//
// Stage/drain (round-3 schedule, known-good):
//   ph1: buf1-A-h0 (pair i)   ph2: buf1-A-h1 (pair i)
//   ph3: buf0-B-h0 (pair i+1) ph4: buf0-B-h1 (i+1); VMC4 drains buf1 pair i
//   ph5: buf0-A-h0 (i+1)      ph6: buf0-A-h1 (i+1)
//   ph7: buf1-B-h0 (i+1)      ph8: buf1-B-h1 (i+1); VMC4 drains buf0 pair i+1

// A fragments for 32x32x16: wave wm's rows; QM picks mtile pair {QM*2, QM*2+1}
template<int BUF, int QM>
DEVFN void ldA(bf16x8 (&a)[2][4], const unsigned short* lds, int wm, int l) {
  const unsigned short* rg = lds + (size_t)(BUF * 4 + wm) * 8192;
#pragma unroll
  for (int mi = 0; mi < 2; ++mi) {
    const int rl = QM * 64 + mi * 32 + (l & 31);
#pragma unroll
    for (int ks = 0; ks < 4; ++ks) {
      const int kel = (ks * 16 + (l >> 5) * 8) ^ ((rl & 7) * 8);
      a[mi][ks] = *(const bf16x8*)(rg + rl * 64 + kel);
    }
  }
}

// B fragments: wave wn's 64 cols = 2 ntiles of 32; QN picks ntile
template<int BUF, int QN>
DEVFN void ldB(bf16x8 (&b)[2][4], const unsigned short* lds, int wn, int l) {
  const unsigned short* rg = lds + (size_t)(BUF * 4 + 2 + (wn >> 1)) * 8192;
  const int cl = (wn & 1) * 64 + QN * 32 + (l & 31);
#pragma unroll
  for (int ks = 0; ks < 4; ++ks) {
    const int kel = (ks * 16 + (l >> 5) * 8) ^ ((cl & 7) * 8);
    b[QN][ks] = *(const bf16x8*)(rg + cl * 64 + kel);
  }
}

template<int QM, int QN>
DEVFN void mfmaQ(f32x16 (&acc)[4][2], bf16x8 (&a)[2][4], bf16x8 (&b)[2][4]) {
  __builtin_amdgcn_s_setprio(1);
#pragma unroll
  for (int ks = 0; ks < 4; ++ks)
#pragma unroll
    for (int mi = 0; mi < 2; ++mi)
      acc[QM * 2 + mi][QN] = __builtin_amdgcn_mfma_f32_32x32x16_bf16(
          a[mi][ks], b[QN][ks], acc[QM * 2 + mi][QN], 0, 0, 0);
  __builtin_amdgcn_s_setprio(0);
}

// C = A (MxK) * W^T (W NxK); bias per col.
//  EPI==0: zOut = bf16(tanh(.))           (zOut = Acat z-half, ldhz stride)
//  EPI==1: u = sigmoid(.); out = u*h + (1-u)*z, h/z read bf16 from hzBuf
template<int EPI>
__global__ __launch_bounds__(512, 1)
void gemm256(const unsigned short* __restrict__ A,
             const unsigned short* __restrict__ W,
             const float* __restrict__ bias,
             int M, int K,
             unsigned short* __restrict__ zOut,
             const unsigned short* __restrict__ hzBuf, int ldhz,
             float* __restrict__ out, int ldo)
{
  __shared__ unsigned short lds[8][8192];
  unsigned short* L = &lds[0][0];

  const int nTM = M >> 8;
  // XCD-chunked swizzle (grid=256, 256%8==0 -> bijective): XCD c gets
  // swz in [32c,32c+32) -> one bn column tile per XCD (B panel L2-resident)
  const int bid = blockIdx.x;
  const int swz = (bid & 7) * (gridDim.x >> 3) + (bid >> 3);
  const int bm = swz % nTM, bn = swz / nTM;
  const int rowBase = bm << 8, colBase = bn << 8;

  const int t = threadIdx.x;
  const int l = t & 63;
  const int w = t >> 6;
  const int wm = w >> 2, wn = w & 3;

  // staging addresses: thread t covers lds elems [t*8, t*8+8) of each 8KB slab
  const int srow = t >> 3;                       // 0..63
  const int scol = (t & 7) * 8;                  // 0..56
  const int kcSrc = scol ^ ((srow & 7) * 8);     // inverse-swizzled source col
  const unsigned short* gA = A + (size_t)(rowBase + srow) * K + kcSrc;
  const unsigned short* gB = W + (size_t)(colBase + srow) * K + kcSrc;

  // STAGE(buf, op, half, kt): one 16KB half-tile, 2 x global_load_lds per thread
#define STAGE(BUF, OP, HALF, KT) do {                                          \
    const unsigned short* gs = ((OP) ? gB : gA)                                \
        + (size_t)((HALF) * 128) * K + (size_t)(KT) * 64;                      \
    unsigned short* ld = L + (size_t)((BUF) * 4 + (OP) * 2 + (HALF)) * 8192    \
        + w * 512;                                                             \
    gload16(gs, ld);                                                           \
    gload16(gs + (size_t)64 * K, ld + 4096);                                   \
  } while (0)

  f32x16 acc[4][2] = {};
  bf16x8 a[2][4], b[2][4];

  // prologue: buf0 pair0 (A h0/h1, B h0/h1) + buf1-B pair0; drain buf0's 8
  STAGE(0, 0, 0, 0); STAGE(0, 0, 1, 0); STAGE(0, 1, 0, 0); STAGE(0, 1, 1, 0);
  STAGE(1, 1, 0, 1); STAGE(1, 1, 1, 1);
  VMC4();
  bar();

  const int NP = K >> 7;   // pairs of BK=64 K-tiles
  for (int i = 0; i < NP; ++i) {
    const bool more = (i + 1 < NP);
    const int ktb1 = 2 * i + 1;                     // buf1-A pair i
    const int kt0n = more ? 2 * i + 2 : 2 * i;      // buf0 pair i+1 (clamped)
    const int kt1n = more ? 2 * i + 3 : 2 * i + 1;  // buf1-B pair i+1 (clamped)

    // ph1: Q(0,0) of buf0
    ldA<0, 0>(a, L, wm, l); ldB<0, 0>(b, L, wn, l);
    STAGE(1, 0, 0, ktb1);
    bar(); LGKM0();
    mfmaQ<0, 0>(acc, a, b);
    bar();
    // ph2: Q(0,1)
    ldB<0, 1>(b, L, wn, l);
    STAGE(1, 0, 1, ktb1);
    bar(); LGKM0();
    mfmaQ<0, 1>(acc, a, b);
    bar();
    // ph3: Q(1,0); buf0-B dead after ph2 -> restage buf0-B h0
    ldA<0, 1>(a, L, wm, l);
    STAGE(0, 1, 0, kt0n);
    bar(); LGKM0();
    mfmaQ<1, 0>(acc, a, b);
    bar();
    // ph4: Q(1,1); restage buf0-B h1; drain so buf1 pair i resident for ph5
    STAGE(0, 1, 1, kt0n);
    bar(); LGKM0();
    mfmaQ<1, 1>(acc, a, b);
    VMC4();
    bar();
    // ph5: Q(0,0) of buf1; buf0-A dead after ph3 -> restage buf0-A h0
    ldA<1, 0>(a, L, wm, l); ldB<1, 0>(b, L, wn, l);
    STAGE(0, 0, 0, kt0n);
    bar(); LGKM0();
    mfmaQ<0, 0>(acc, a, b);
    bar();
    // ph6: Q(0,1); restage buf0-A h1
    ldB<1, 1>(b, L, wn, l);
    STAGE(0, 0, 1, kt0n);
    bar(); LGKM0();
    mfmaQ<0, 1>(acc, a, b);
    bar();
    // ph7: Q(1,0); buf1-B dead after ph6 -> restage buf1-B h0
    ldA<1, 1>(a, L, wm, l);
    STAGE(1, 1, 0, kt1n);
    bar(); LGKM0();
    mfmaQ<1, 0>(acc, a, b);
    bar();
    // ph8: Q(1,1); restage buf1-B h1; drain buf0 pair i+1 before next ph1
    STAGE(1, 1, 1, kt1n);
    bar(); LGKM0();
    mfmaQ<1, 1>(acc, a, b);
    VMC4();
    bar();
  }
#undef STAGE

  // epilogue; 32x32 C/D layout [HW-verified m74/m101]:
  //   col = lane&31, row = (reg&3) + 8*(reg>>2) + 4*(lane>>5), reg in [0,16)
#pragma unroll
  for (int nt = 0; nt < 2; ++nt) {
    const int c = colBase + wn * 64 + nt * 32 + (l & 31);
    const float bs = bias[c];
#pragma unroll
    for (int mt = 0; mt < 4; ++mt) {
      const int rb = rowBase + wm * 128 + mt * 32 + 4 * (l >> 5);
#pragma unroll
      for (int reg = 0; reg < 16; ++reg) {
        const int r = rb + (reg & 3) + 8 * (reg >> 2);
        const float pre = acc[mt][nt][reg] + bs;
        if (EPI == 0) {
          zOut[(size_t)r * ldhz + c] = f32_to_bf16(tanhf(pre));
        } else {
          const float u = 1.0f / (1.0f + __expf(-pre));
          const float hv = bf16_to_f32(hzBuf[(size_t)r * ldhz + c]);
          const float zv = bf16_to_f32(hzBuf[(size_t)r * ldhz + 2048 + c]);
          out[(size_t)r * ldo + c] = u * hv + (1.0f - u) * zv;
        }
      }
    }
  }
}

extern "C" void kernel_launch(void* const* d_in, const int* in_sizes, int n_in,
                              void* d_out, int out_size, void* d_ws, size_t ws_size,
                              hipStream_t stream) {
  const float* h  = (const float*)d_in[0];   // (B,H)
  const float* x  = (const float*)d_in[1];   // (B,IN)
  const float* Wx = (const float*)d_in[2];   // (H,IN)
  const float* bx = (const float*)d_in[3];   // (H)
  const float* Wh = (const float*)d_in[4];   // (H,H)
  const float* Uz = (const float*)d_in[5];   // (H,H)
  const float* bu = (const float*)d_in[6];   // (H)
  float* out = (float*)d_out;

  unsigned short* ws   = (unsigned short*)d_ws;
  unsigned short* xb   = ws;                          // B*IN
  unsigned short* Wxb  = xb + (size_t)kB * kIN;       // H*IN
  unsigned short* Wcat = Wxb + (size_t)kH * kIN;      // H*2H  ([Wh|Uz])
  unsigned short* Acat = Wcat + (size_t)kH * 2 * kH;  // B*2H  ([h|z])

  // all fp32->bf16 casts in one pass: 8,912,896 vec4 units / 256 = 34816 blocks
  cast_all<<<34816, 256, 0, stream>>>(x, Wx, Wh, Uz, h, xb, Wxb, Wcat, Acat);

  const int grid = (kB / 256) * (kH / 256);  // 32 * 8 = 256 = 1 block/CU

  // GEMM1: z = tanh(x Wx^T + bx) -> bf16 into Acat[:, H:2H]
  gemm256<0><<<grid, 512, 0, stream>>>(
      xb, Wxb, bx, kB, kIN, Acat + kH, nullptr, 2 * kH, nullptr, 0);

  // GEMM2: u = sigmoid([h|z] [Wh|Uz]^T + bu); out = u*h + (1-u)*z (h,z bf16)
  gemm256<1><<<grid, 512, 0, stream>>>(
      Acat, Wcat, bu, kB, 2 * kH, nullptr, Acat, 2 * kH, out, kH);
}

// Round 6
// 213.922 us; speedup vs baseline: 1.5258x; 1.5258x over previous
//
#include <hip/hip_runtime.h>
#include <hip/hip_bf16.h>
#include <cstdint>
#include <cstddef>

#define DEVFN static __device__ __forceinline__

typedef __attribute__((ext_vector_type(8))) short bf16x8;
typedef __attribute__((ext_vector_type(4))) float f32x4;

static constexpr int kB = 8192;
static constexpr int kIN = 1024;
static constexpr int kH = 2048;

DEVFN unsigned short f32_to_bf16(float f) {
  union { float f; unsigned int u; } v; v.f = f;
  unsigned int x = v.u;
  x += 0x7fffu + ((x >> 16) & 1u);   // round-to-nearest-even
  return (unsigned short)(x >> 16);
}
DEVFN float bf16_to_f32(unsigned short u) {
  union { unsigned int u; float f; } v; v.u = (unsigned int)u << 16;
  return v.f;
}

// one fused cast pass: fp32 -> bf16 for all five panels (vec4 per thread)
__global__ void cast_all(const float* __restrict__ x, const float* __restrict__ Wx,
                         const float* __restrict__ Wh, const float* __restrict__ Uz,
                         const float* __restrict__ h,
                         unsigned short* __restrict__ xb, unsigned short* __restrict__ Wxb,
                         unsigned short* __restrict__ Wcat, unsigned short* __restrict__ Acat) {
  const long i = (long)blockIdx.x * blockDim.x + threadIdx.x;  // vec4 index
  const float* src; unsigned short* dst; int sh, stride, off; long li;
  if (i < 2097152L)      { li = i;            src = x;  dst = xb;   sh = 8; stride = 1024; off = 0; }
  else if (i < 2621440L) { li = i - 2097152L; src = Wx; dst = Wxb;  sh = 8; stride = 1024; off = 0; }
  else if (i < 3670016L) { li = i - 2621440L; src = Wh; dst = Wcat; sh = 9; stride = 4096; off = 0; }
  else if (i < 4718592L) { li = i - 3670016L; src = Uz; dst = Wcat; sh = 9; stride = 4096; off = 2048; }
  else                   { li = i - 4718592L; src = h;  dst = Acat; sh = 9; stride = 4096; off = 0; }
  float4 v = *(const float4*)(src + li * 4);
  const long row = li >> sh;
  const long col = (li & ((1L << sh) - 1)) * 4;
  unsigned short* d = dst + row * stride + off + col;
  ushort4 o;
  o.x = f32_to_bf16(v.x); o.y = f32_to_bf16(v.y);
  o.z = f32_to_bf16(v.z); o.w = f32_to_bf16(v.w);
  *(ushort4*)d = o;
}

typedef const __attribute__((address_space(1))) unsigned int* gptr_t;
typedef __attribute__((address_space(3))) unsigned int* lptr_t;
DEVFN void gload16(const unsigned short* g, unsigned short* l) {
  __builtin_amdgcn_global_load_lds((gptr_t)g, (lptr_t)l, 16, 0, 0);
}

DEVFN void bar() { __builtin_amdgcn_s_barrier(); }
#define LGKM0() asm volatile("s_waitcnt lgkmcnt(0)" ::: "memory")
#define VMC6()  asm volatile("s_waitcnt vmcnt(6)" ::: "memory")

// LDS geometry: 8 regions of [128 rows][64 bf16] (16 KiB each) = 128 KiB.
// region = buf*4 + op*2 + half   (op: 0=A, 1=B; half: rows 0-127 / 128-255)
// Swizzle (T2): element col stored at  c ^ ((row&7)*8)  (byte ^= (row&7)<<4).
// global_load_lds writes LINEAR; global SOURCE col is pre-swizzled (rule 21).
//
// Stage/drain schedule (max-min-age under writable/deadline constraints):
//   region dead points: buf0-B after ph2, buf0-A after ph3,
//                       buf1-B after ph6, buf1-A after ph7.
//   stages: ph1=A1h1(tile 2i+1), ph3=B0'h0, ph4=B0'h1+A0'h0, ph5=A0'h1,
//           ph7=B1'h0, ph8=B1'h1+A1'h0   (buf0'=2i+2, buf1'=2i+3)
//   drains: vmcnt(6) at ph4 (completes buf1 pair 2i+1; youngest = age 3)
//           vmcnt(6) at ph8 (completes buf0' pair 2i+2; youngest = age 3)
//   14 loads in flight at drains; min drained-load age = 3 phases (~465cy),
//   covering L3-hit latency (per-XCD demand 24MB >> 4MB L2 -> loads hit L3).

template<int BUF, int QM>
DEVFN void ldA(bf16x8 (&a)[4][2], const unsigned short* lds, int wm, int lr, int lg) {
  const unsigned short* rg = lds + (size_t)(BUF * 4 + wm) * 8192;
#pragma unroll
  for (int mi = 0; mi < 4; ++mi) {
    const int rl = QM * 64 + mi * 16 + lr;
#pragma unroll
    for (int kk = 0; kk < 2; ++kk) {
      const int kel = (kk * 32 + lg * 8) ^ ((rl & 7) * 8);
      a[mi][kk] = *(const bf16x8*)(rg + rl * 64 + kel);
    }
  }
}

template<int BUF, int QN>
DEVFN void ldB(bf16x8 (&b)[4][2], const unsigned short* lds, int wn, int lr, int lg) {
  const unsigned short* rg = lds + (size_t)(BUF * 4 + 2 + (wn >> 1)) * 8192;
#pragma unroll
  for (int ni = 0; ni < 2; ++ni) {
    const int n = QN * 2 + ni;
    const int cl = (wn & 1) * 64 + n * 16 + lr;
#pragma unroll
    for (int kk = 0; kk < 2; ++kk) {
      const int kel = (kk * 32 + lg * 8) ^ ((cl & 7) * 8);
      b[n][kk] = *(const bf16x8*)(rg + cl * 64 + kel);
    }
  }
}

template<int QM, int QN>
DEVFN void mfmaQ(f32x4 (&acc)[8][4], bf16x8 (&a)[4][2], bf16x8 (&b)[4][2]) {
  __builtin_amdgcn_s_setprio(1);
#pragma unroll
  for (int mi = 0; mi < 4; ++mi)
#pragma unroll
    for (int ni = 0; ni < 2; ++ni)
#pragma unroll
      for (int kk = 0; kk < 2; ++kk)
        acc[QM * 4 + mi][QN * 2 + ni] = __builtin_amdgcn_mfma_f32_16x16x32_bf16(
            a[mi][kk], b[QN * 2 + ni][kk], acc[QM * 4 + mi][QN * 2 + ni], 0, 0, 0);
  __builtin_amdgcn_s_setprio(0);
}

// C = A (MxK) * W^T (W NxK); bias per col.
//  EPI==0: zOut = bf16(tanh(.))           (zOut = Acat z-half, ldhz stride)
//  EPI==1: u = sigmoid(.); out = u*h + (1-u)*z, h/z read bf16 from hzBuf
template<int EPI>
__global__ __launch_bounds__(512, 1)
void gemm256(const unsigned short* __restrict__ A,
             const unsigned short* __restrict__ W,
             const float* __restrict__ bias,
             int M, int K,
             unsigned short* __restrict__ zOut,
             const unsigned short* __restrict__ hzBuf, int ldhz,
             float* __restrict__ out, int ldo)
{
  __shared__ unsigned short lds[8][8192];
  unsigned short* L = &lds[0][0];

  const int nTM = M >> 8;
  const int bm = blockIdx.x % nTM, bn = blockIdx.x / nTM;   // default map: ~4bm x 8bn per XCD (near-optimal)
  const int rowBase = bm << 8, colBase = bn << 8;

  const int t = threadIdx.x;
  const int l = t & 63;
  const int w = t >> 6;
  const int lr = l & 15, lg = l >> 4;
  const int wm = w >> 2, wn = w & 3;

  // staging addresses: thread t covers lds elems [t*8, t*8+8) of each 8KB slab
  const int srow = t >> 3;                       // 0..63
  const int scol = (t & 7) * 8;                  // 0..56
  const int kcSrc = scol ^ ((srow & 7) * 8);     // inverse-swizzled source col
  const unsigned short* gA = A + (size_t)(rowBase + srow) * K + kcSrc;
  const unsigned short* gB = W + (size_t)(colBase + srow) * K + kcSrc;

  // STAGE(buf, op, half, kt): one 16KB half-tile, 2 x global_load_lds per thread
#define STAGE(BUF, OP, HALF, KT) do {                                          \
    const unsigned short* gs = ((OP) ? gB : gA)                                \
        + (size_t)((HALF) * 128) * K + (size_t)(KT) * 64;                      \
    unsigned short* ld = L + (size_t)((BUF) * 4 + (OP) * 2 + (HALF)) * 8192    \
        + w * 512;                                                             \
    gload16(gs, ld);                                                           \
    gload16(gs + (size_t)64 * K, ld + 4096);                                   \
  } while (0)

  f32x4 acc[8][4] = {};
  bf16x8 a[4][2], b[4][2];

  // prologue: buf0 pair0 (4 half-tiles), then buf1-B(2) + buf1-A h0 (tile 1);
  // vmcnt(6) completes exactly the 8 buf0 loads.
  STAGE(0, 0, 0, 0); STAGE(0, 0, 1, 0); STAGE(0, 1, 0, 0); STAGE(0, 1, 1, 0);
  STAGE(1, 1, 0, 1); STAGE(1, 1, 1, 1); STAGE(1, 0, 0, 1);
  VMC6();
  bar();

  const int NP = K >> 7;   // pairs of BK=64 K-tiles
  for (int i = 0; i < NP; ++i) {
    const bool more = (i + 1 < NP);
    const int ktb1 = 2 * i + 1;                     // buf1-A h1, pair-tile 2i+1
    const int kt0n = more ? 2 * i + 2 : 2 * i;      // buf0' (clamped: restage)
    const int kt1n = more ? 2 * i + 3 : 2 * i + 1;  // buf1' (clamped)

    // ph1: Q(0,0) of buf0; stage buf1-A h1 (completes buf1 pair 2i+1 issue)
    ldA<0, 0>(a, L, wm, lr, lg); ldB<0, 0>(b, L, wn, lr, lg);
    STAGE(1, 0, 1, ktb1);
    bar(); LGKM0();
    mfmaQ<0, 0>(acc, a, b);
    bar();
    // ph2: Q(0,1); no stage
    ldB<0, 1>(b, L, wn, lr, lg);
    bar(); LGKM0();
    mfmaQ<0, 1>(acc, a, b);
    bar();
    // ph3: Q(1,0); buf0-B dead after ph2 -> stage B0'h0
    ldA<0, 1>(a, L, wm, lr, lg);
    STAGE(0, 1, 0, kt0n);
    bar(); LGKM0();
    mfmaQ<1, 0>(acc, a, b);
    bar();
    // ph4: Q(1,1); stage B0'h1 + A0'h0 (buf0-A dead after ph3);
    //      vmcnt(6) drains buf1 pair 2i+1 (youngest load age 3 phases)
    STAGE(0, 1, 1, kt0n);
    STAGE(0, 0, 0, kt0n);
    bar(); LGKM0();
    mfmaQ<1, 1>(acc, a, b);
    VMC6();
    bar();
    // ph5: Q(0,0) of buf1; stage A0'h1
    ldA<1, 0>(a, L, wm, lr, lg); ldB<1, 0>(b, L, wn, lr, lg);
    STAGE(0, 0, 1, kt0n);
    bar(); LGKM0();
    mfmaQ<0, 0>(acc, a, b);
    bar();
    // ph6: Q(0,1); no stage
    ldB<1, 1>(b, L, wn, lr, lg);
    bar(); LGKM0();
    mfmaQ<0, 1>(acc, a, b);
    bar();
    // ph7: Q(1,0); buf1-B dead after ph6 -> stage B1'h0
    ldA<1, 1>(a, L, wm, lr, lg);
    STAGE(1, 1, 0, kt1n);
    bar(); LGKM0();
    mfmaQ<1, 0>(acc, a, b);
    bar();
    // ph8: Q(1,1); stage B1'h1 + A1'h0 (buf1-A dead after ph7);
    //      vmcnt(6) drains buf0' pair 2i+2 before next ph1
    STAGE(1, 1, 1, kt1n);
    STAGE(1, 0, 0, kt1n);
    bar(); LGKM0();
    mfmaQ<1, 1>(acc, a, b);
    VMC6();
    bar();
  }
#undef STAGE

  // epilogue; C/D layout: col = lane&15, row = (lane>>4)*4 + reg  [HW-verified]
#pragma unroll
  for (int m = 0; m < 8; ++m) {
    const int r0 = rowBase + wm * 128 + m * 16 + lg * 4;
#pragma unroll
    for (int n = 0; n < 4; ++n) {
      const int c = colBase + wn * 64 + n * 16 + lr;
      const float bs = bias[c];
#pragma unroll
      for (int q = 0; q < 4; ++q) {
        const int r = r0 + q;
        const float pre = acc[m][n][q] + bs;
        if (EPI == 0) {
          zOut[(size_t)r * ldhz + c] = f32_to_bf16(tanhf(pre));
        } else {
          const float u = 1.0f / (1.0f + __expf(-pre));
          const float hv = bf16_to_f32(hzBuf[(size_t)r * ldhz + c]);
          const float zv = bf16_to_f32(hzBuf[(size_t)r * ldhz + 2048 + c]);
          out[(size_t)r * ldo + c] = u * hv + (1.0f - u) * zv;
        }
      }
    }
  }
}

extern "C" void kernel_launch(void* const* d_in, const int* in_sizes, int n_in,
                              void* d_out, int out_size, void* d_ws, size_t ws_size,
                              hipStream_t stream) {
  const float* h  = (const float*)d_in[0];   // (B,H)
  const float* x  = (const float*)d_in[1];   // (B,IN)
  const float* Wx = (const float*)d_in[2];   // (H,IN)
  const float* bx = (const float*)d_in[3];   // (H)
  const float* Wh = (const float*)d_in[4];   // (H,H)
  const float* Uz = (const float*)d_in[5];   // (H,H)
  const float* bu = (const float*)d_in[6];   // (H)
  float* out = (float*)d_out;

  unsigned short* ws   = (unsigned short*)d_ws;
  unsigned short* xb   = ws;                          // B*IN
  unsigned short* Wxb  = xb + (size_t)kB * kIN;       // H*IN
  unsigned short* Wcat = Wxb + (size_t)kH * kIN;      // H*2H  ([Wh|Uz])
  unsigned short* Acat = Wcat + (size_t)kH * 2 * kH;  // B*2H  ([h|z])

  // all fp32->bf16 casts in one pass: 8,912,896 vec4 units / 256 = 34816 blocks
  cast_all<<<34816, 256, 0, stream>>>(x, Wx, Wh, Uz, h, xb, Wxb, Wcat, Acat);

  const int grid = (kB / 256) * (kH / 256);  // 32 * 8 = 256 = 1 block/CU

  // GEMM1: z = tanh(x Wx^T + bx) -> bf16 into Acat[:, H:2H]
  gemm256<0><<<grid, 512, 0, stream>>>(
      xb, Wxb, bx, kB, kIN, Acat + kH, nullptr, 2 * kH, nullptr, 0);

  // GEMM2: u = sigmoid([h|z] [Wh|Uz]^T + bu); out = u*h + (1-u)*z (h,z bf16)
  gemm256<1><<<grid, 512, 0, stream>>>(
      Acat, Wcat, bu, kB, 2 * kH, nullptr, Acat, 2 * kH, out, kH);
}

// Round 7
// 205.937 us; speedup vs baseline: 1.5849x; 1.0388x over previous
//
#include <hip/hip_runtime.h>
#include <hip/hip_bf16.h>
#include <cstdint>
#include <cstddef>

#define DEVFN static __device__ __forceinline__

typedef __attribute__((ext_vector_type(8))) short bf16x8;
typedef __attribute__((ext_vector_type(4))) float f32x4;

static constexpr int kB = 8192;
static constexpr int kIN = 1024;
static constexpr int kH = 2048;

DEVFN unsigned short f32_to_bf16(float f) {
  union { float f; unsigned int u; } v; v.f = f;
  unsigned int x = v.u;
  x += 0x7fffu + ((x >> 16) & 1u);   // round-to-nearest-even
  return (unsigned short)(x >> 16);
}
DEVFN float bf16_to_f32(unsigned short u) {
  union { unsigned int u; float f; } v; v.u = (unsigned int)u << 16;
  return v.f;
}

// one fused cast pass: fp32 -> bf16 for all five panels (vec4 per thread)
__global__ void cast_all(const float* __restrict__ x, const float* __restrict__ Wx,
                         const float* __restrict__ Wh, const float* __restrict__ Uz,
                         const float* __restrict__ h,
                         unsigned short* __restrict__ xb, unsigned short* __restrict__ Wxb,
                         unsigned short* __restrict__ Wcat, unsigned short* __restrict__ Acat) {
  const long i = (long)blockIdx.x * blockDim.x + threadIdx.x;  // vec4 index
  const float* src; unsigned short* dst; int sh, stride, off; long li;
  if (i < 2097152L)      { li = i;            src = x;  dst = xb;   sh = 8; stride = 1024; off = 0; }
  else if (i < 2621440L) { li = i - 2097152L; src = Wx; dst = Wxb;  sh = 8; stride = 1024; off = 0; }
  else if (i < 3670016L) { li = i - 2621440L; src = Wh; dst = Wcat; sh = 9; stride = 4096; off = 0; }
  else if (i < 4718592L) { li = i - 3670016L; src = Uz; dst = Wcat; sh = 9; stride = 4096; off = 2048; }
  else                   { li = i - 4718592L; src = h;  dst = Acat; sh = 9; stride = 4096; off = 0; }
  float4 v = *(const float4*)(src + li * 4);
  const long row = li >> sh;
  const long col = (li & ((1L << sh) - 1)) * 4;
  unsigned short* d = dst + row * stride + off + col;
  ushort4 o;
  o.x = f32_to_bf16(v.x); o.y = f32_to_bf16(v.y);
  o.z = f32_to_bf16(v.z); o.w = f32_to_bf16(v.w);
  *(ushort4*)d = o;
}

typedef const __attribute__((address_space(1))) unsigned int* gptr_t;
typedef __attribute__((address_space(3))) unsigned int* lptr_t;
DEVFN void gload16(const unsigned short* g, unsigned short* l) {
  __builtin_amdgcn_global_load_lds((gptr_t)g, (lptr_t)l, 16, 0, 0);
}

DEVFN void bar() { __builtin_amdgcn_s_barrier(); }
#define VMC0() asm volatile("s_waitcnt vmcnt(0)" ::: "memory")
#define VMC2() asm volatile("s_waitcnt vmcnt(2)" ::: "memory")

// LDS geometry: 8 regions of [128 rows][64 bf16] (16 KiB each) = 128 KiB.
// region = buf*4 + op*2 + half   (op: 0=A, 1=B; half: rows 0-127 / 128-255)
// Swizzle (T2): element col stored at  c ^ ((row&7)*8).
// global_load_lds writes LINEAR; global SOURCE col is pre-swizzled (rule 21).
//
// ONE-PHASE-AHEAD fragment pipeline (this round's change):
//   quadrant order per K-tile: Q00,Q01,Q10,Q11.  Single a[4][2] bank,
//   reloaded POST-MFMA at ph2/4/6/8 (WAR-safe: after last use);
//   b halves reloaded PRE-MFMA at ph1/4/5/8 (into the half not used for
//   2 phases).  Per-phase ds_read counts: 4,8,2*,8,4,8,2*,8+4 — every read
//   issued >=1 phase before its consuming MFMA; NO manual lgkmcnt: the
//   compiler inserts minimal counted waits, so LDS reads overlap MFMA.
//   Stage plan (2 gloads/phase; ph8 has 4):
//     ph1=A1h1(2j+1), ph3=B0'h0, ph4=B0'h1, ph5=A0'h0, ph6=A0'h1,
//     ph7=B1'h0, ph8=B1'h1+A1'h0            (buf0'=2j+2, buf1'=2j+3)
//   Drains: vmcnt(2) at ph3-end (retires buf1' = ph7,ph8 prev + ph1) and
//   vmcnt(2) at ph7-end (retires buf0' = ph3..ph6).  Never vmcnt(0),
//   never drain a same-phase load.

template<int BUF, int QM>
DEVFN void ldA(bf16x8 (&a)[4][2], const unsigned short* lds, int wm, int lr, int lg) {
  const unsigned short* rg = lds + (size_t)(BUF * 4 + wm) * 8192;
#pragma unroll
  for (int mi = 0; mi < 4; ++mi) {
    const int rl = QM * 64 + mi * 16 + lr;
#pragma unroll
    for (int kk = 0; kk < 2; ++kk) {
      const int kel = (kk * 32 + lg * 8) ^ ((rl & 7) * 8);
      a[mi][kk] = *(const bf16x8*)(rg + rl * 64 + kel);
    }
  }
}

template<int BUF, int QN>
DEVFN void ldB(bf16x8 (&b)[4][2], const unsigned short* lds, int wn, int lr, int lg) {
  const unsigned short* rg = lds + (size_t)(BUF * 4 + 2 + (wn >> 1)) * 8192;
#pragma unroll
  for (int ni = 0; ni < 2; ++ni) {
    const int n = QN * 2 + ni;
    const int cl = (wn & 1) * 64 + n * 16 + lr;
#pragma unroll
    for (int kk = 0; kk < 2; ++kk) {
      const int kel = (kk * 32 + lg * 8) ^ ((cl & 7) * 8);
      b[n][kk] = *(const bf16x8*)(rg + cl * 64 + kel);
    }
  }
}

template<int QM, int QN>
DEVFN void mfmaQ(f32x4 (&acc)[8][4], bf16x8 (&a)[4][2], bf16x8 (&b)[4][2]) {
  __builtin_amdgcn_s_setprio(1);
#pragma unroll
  for (int mi = 0; mi < 4; ++mi)
#pragma unroll
    for (int ni = 0; ni < 2; ++ni)
#pragma unroll
      for (int kk = 0; kk < 2; ++kk)
        acc[QM * 4 + mi][QN * 2 + ni] = __builtin_amdgcn_mfma_f32_16x16x32_bf16(
            a[mi][kk], b[QN * 2 + ni][kk], acc[QM * 4 + mi][QN * 2 + ni], 0, 0, 0);
  __builtin_amdgcn_s_setprio(0);
}

// C = A (MxK) * W^T (W NxK); bias per col.
//  EPI==0: zOut = bf16(tanh(.))           (zOut = Acat z-half, ldhz stride)
//  EPI==1: u = sigmoid(.); out = u*h + (1-u)*z, h/z read bf16 from hzBuf
template<int EPI>
__global__ __launch_bounds__(512, 1)
void gemm256(const unsigned short* __restrict__ A,
             const unsigned short* __restrict__ W,
             const float* __restrict__ bias,
             int M, int K,
             unsigned short* __restrict__ zOut,
             const unsigned short* __restrict__ hzBuf, int ldhz,
             float* __restrict__ out, int ldo)
{
  __shared__ unsigned short lds[8][8192];
  unsigned short* L = &lds[0][0];

  const int nTM = M >> 8;
  const int bm = blockIdx.x % nTM, bn = blockIdx.x / nTM;
  const int rowBase = bm << 8, colBase = bn << 8;

  const int t = threadIdx.x;
  const int l = t & 63;
  const int w = t >> 6;
  const int lr = l & 15, lg = l >> 4;
  const int wm = w >> 2, wn = w & 3;

  // staging addresses: thread t covers lds elems [t*8, t*8+8) of each 8KB slab
  const int srow = t >> 3;                       // 0..63
  const int scol = (t & 7) * 8;                  // 0..56
  const int kcSrc = scol ^ ((srow & 7) * 8);     // inverse-swizzled source col
  const unsigned short* gA = A + (size_t)(rowBase + srow) * K + kcSrc;
  const unsigned short* gB = W + (size_t)(colBase + srow) * K + kcSrc;

  // STAGE(buf, op, half, kt): one 16KB half-tile, 2 x global_load_lds per thread
#define STAGE(BUF, OP, HALF, KT) do {                                          \
    const unsigned short* gs = ((OP) ? gB : gA)                                \
        + (size_t)((HALF) * 128) * K + (size_t)(KT) * 64;                      \
    unsigned short* ld = L + (size_t)((BUF) * 4 + (OP) * 2 + (HALF)) * 8192    \
        + w * 512;                                                             \
    gload16(gs, ld);                                                           \
    gload16(gs + (size_t)64 * K, ld + 4096);                                   \
  } while (0)

  f32x4 acc[8][4] = {};
  bf16x8 a[4][2], b[4][2];

  // prologue: stage buf0=tile0, buf1=tile1 fully; drain; preload a=A0b0, b01=B0b0
  STAGE(0, 1, 0, 0); STAGE(0, 1, 1, 0); STAGE(0, 0, 0, 0); STAGE(0, 0, 1, 0);
  STAGE(1, 1, 0, 1); STAGE(1, 1, 1, 1); STAGE(1, 0, 0, 1); STAGE(1, 0, 1, 1);
  VMC0();
  bar();
  ldA<0, 0>(a, L, wm, lr, lg);
  ldB<0, 0>(b, L, wn, lr, lg);

  const int NP = K >> 7;   // pairs of BK=64 K-tiles
  for (int j = 0; j < NP; ++j) {
    const bool more = (j + 1 < NP);
    const int ktb1 = 2 * j + 1;                     // buf1-A h1 (this pair; j=0: benign rewrite)
    const int kt0n = more ? 2 * j + 2 : 2 * j;      // buf0' (clamped: benign identical restage)
    const int kt1n = more ? 2 * j + 3 : 2 * j + 1;  // buf1' (clamped)

    // ph1: Q00-b0.  pre: B1b0 -> b23 (used ph2/ph4).  stage A1h1.
    ldB<0, 1>(b, L, wn, lr, lg);
    STAGE(1, 0, 1, ktb1);
    bar();
    mfmaQ<0, 0>(acc, a, b);
    bar();
    // ph2: Q01-b0.  post: a <- A1b0 (used ph3/ph4; WAR-safe after MFMA).
    bar();
    mfmaQ<0, 1>(acc, a, b);
    ldA<0, 1>(a, L, wm, lr, lg);
    bar();
    // ph3: Q10-b0.  stage B0'h0.  drain buf1' (ph7/ph8 prev + ph1) = vmcnt(2).
    STAGE(0, 1, 0, kt0n);
    bar();
    mfmaQ<1, 0>(acc, a, b);
    VMC2();
    bar();
    // ph4: Q11-b0.  pre: B0b1 -> b01 (b01 dead after ph3; used ph5/ph7).
    //      stage B0'h1.  post: a <- A0b1 (buf1 resident since ph3 drain).
    ldB<1, 0>(b, L, wn, lr, lg);
    STAGE(0, 1, 1, kt0n);
    bar();
    mfmaQ<1, 1>(acc, a, b);
    ldA<1, 0>(a, L, wm, lr, lg);
    bar();
    // ph5: Q00-b1.  pre: B1b1 -> b23 (dead after ph4; used ph6/ph8).  stage A0'h0.
    ldB<1, 1>(b, L, wn, lr, lg);
    STAGE(0, 0, 0, kt0n);
    bar();
    mfmaQ<0, 0>(acc, a, b);
    bar();
    // ph6: Q01-b1.  stage A0'h1.  post: a <- A1b1 (used ph7/ph8).
    STAGE(0, 0, 1, kt0n);
    bar();
    mfmaQ<0, 1>(acc, a, b);
    ldA<1, 1>(a, L, wm, lr, lg);
    bar();
    // ph7: Q10-b1.  stage B1'h0.  drain buf0' (ph3..ph6) = vmcnt(2).
    STAGE(1, 1, 0, kt1n);
    bar();
    mfmaQ<1, 0>(acc, a, b);
    VMC2();
    bar();
    // ph8: Q11-b1.  pre: B0 of next pair -> b01 (b01 dead after ph7; buf0'
    //      drained at ph7).  stage B1'h1 + A1'h0.  post: a <- A0 next pair.
    ldB<0, 0>(b, L, wn, lr, lg);
    STAGE(1, 1, 1, kt1n);
    STAGE(1, 0, 0, kt1n);
    bar();
    mfmaQ<1, 1>(acc, a, b);
    ldA<0, 0>(a, L, wm, lr, lg);
    bar();
  }
#undef STAGE

  // epilogue; C/D layout: col = lane&15, row = (lane>>4)*4 + reg  [HW-verified]
#pragma unroll
  for (int m = 0; m < 8; ++m) {
    const int r0 = rowBase + wm * 128 + m * 16 + lg * 4;
#pragma unroll
    for (int n = 0; n < 4; ++n) {
      const int c = colBase + wn * 64 + n * 16 + lr;
      const float bs = bias[c];
#pragma unroll
      for (int q = 0; q < 4; ++q) {
        const int r = r0 + q;
        const float pre = acc[m][n][q] + bs;
        if (EPI == 0) {
          zOut[(size_t)r * ldhz + c] = f32_to_bf16(tanhf(pre));
        } else {
          const float u = 1.0f / (1.0f + __expf(-pre));
          const float hv = bf16_to_f32(hzBuf[(size_t)r * ldhz + c]);
          const float zv = bf16_to_f32(hzBuf[(size_t)r * ldhz + 2048 + c]);
          out[(size_t)r * ldo + c] = u * hv + (1.0f - u) * zv;
        }
      }
    }
  }
}

extern "C" void kernel_launch(void* const* d_in, const int* in_sizes, int n_in,
                              void* d_out, int out_size, void* d_ws, size_t ws_size,
                              hipStream_t stream) {
  const float* h  = (const float*)d_in[0];   // (B,H)
  const float* x  = (const float*)d_in[1];   // (B,IN)
  const float* Wx = (const float*)d_in[2];   // (H,IN)
  const float* bx = (const float*)d_in[3];   // (H)
  const float* Wh = (const float*)d_in[4];   // (H,H)
  const float* Uz = (const float*)d_in[5];   // (H,H)
  const float* bu = (const float*)d_in[6];   // (H)
  float* out = (float*)d_out;

  unsigned short* ws   = (unsigned short*)d_ws;
  unsigned short* xb   = ws;                          // B*IN
  unsigned short* Wxb  = xb + (size_t)kB * kIN;       // H*IN
  unsigned short* Wcat = Wxb + (size_t)kH * kIN;      // H*2H  ([Wh|Uz])
  unsigned short* Acat = Wcat + (size_t)kH * 2 * kH;  // B*2H  ([h|z])

  // all fp32->bf16 casts in one pass: 8,912,896 vec4 units / 256 = 34816 blocks
  cast_all<<<34816, 256, 0, stream>>>(x, Wx, Wh, Uz, h, xb, Wxb, Wcat, Acat);

  const int grid = (kB / 256) * (kH / 256);  // 32 * 8 = 256 = 1 block/CU

  // GEMM1: z = tanh(x Wx^T + bx) -> bf16 into Acat[:, H:2H]
  gemm256<0><<<grid, 512, 0, stream>>>(
      xb, Wxb, bx, kB, kIN, Acat + kH, nullptr, 2 * kH, nullptr, 0);

  // GEMM2: u = sigmoid([h|z] [Wh|Uz]^T + bu); out = u*h + (1-u)*z (h,z bf16)
  gemm256<1><<<grid, 512, 0, stream>>>(
      Acat, Wcat, bu, kB, 2 * kH, nullptr, Acat, 2 * kH, out, kH);
}